// Round 3
// baseline (6185.933 us; speedup 1.0000x reference)
//
#include <hip/hip_runtime.h>

#define NROWS 131072
#define DIM   128
#define FFD   512
#define TSTEPS 4
#define NBLK  512
#define CHUNK 64
#define NCHUNK 4   // NROWS / (NBLK*CHUNK)
#define NSLOT 16

static_assert((long)NBLK * CHUNK * NCHUNK == NROWS, "grid/chunk mismatch");

// ---------------------------------------------------------------------------
// Kernel A (fp32): LN1, K/V projections, per-block partial K^T@V -> atomic slots
// ---------------------------------------------------------------------------
__global__ __launch_bounds__(256, 1)
void kA32(const float* __restrict__ x, const float* __restrict__ Kw,
          const float* __restrict__ Vw, const float* __restrict__ ga,
          const float* __restrict__ be, float* __restrict__ slots)
{
    __shared__ float hb[CHUNK*DIM];   // LN1 output tile
    __shared__ float Kt[CHUNK*DIM];   // K tile (row-major [r][n])
    __shared__ float Vt[CHUNK*DIM];   // V tile
    const int tid  = threadIdx.x;
    const int wv   = tid >> 6, lane = tid & 63;
    const int i    = tid & 127;              // KtV row (K-column) this thread owns
    const int j0   = (tid >> 7) * 64;        // KtV col block [j0, j0+64)
    const int cc   = (tid & 31) * 4;         // projection col base
    const int rr8  = (tid >> 5) * 8;         // projection row base

    float accP[64];                          // KtV partial: row i, cols j0..j0+63
    #pragma unroll
    for (int p = 0; p < 64; ++p) accP[p] = 0.f;

    const float g0 = ga[2*lane], g1 = ga[2*lane+1];
    const float b0 = be[2*lane], b1v = be[2*lane+1];

    for (int ch = 0; ch < NCHUNK; ++ch) {
        const size_t r0 = ((size_t)blockIdx.x * NCHUNK + ch) * CHUNK;
        // --- LN1 straight from global: one wave per row, 2 elems/lane ---
        for (int rr = 0; rr < 16; ++rr) {
            const int r = wv*16 + rr;
            const float2 xv = *(const float2*)(x + (r0 + r)*DIM + 2*lane);
            float s = xv.x + xv.y;
            float q = xv.x*xv.x + xv.y*xv.y;
            #pragma unroll
            for (int o = 1; o < 64; o <<= 1) { s += __shfl_xor(s, o); q += __shfl_xor(q, o); }
            const float m  = s * (1.0f/128.0f);
            const float rs = rsqrtf(q * (1.0f/128.0f) - m*m + 1e-5f);
            hb[r*DIM + 2*lane]     = (xv.x - m)*rs*g0 + b0;
            hb[r*DIM + 2*lane + 1] = (xv.y - m)*rs*g1 + b1v;
        }
        __syncthreads();
        // --- K = h@Kw, V = h@Vw (fp32): thread -> rows rr8..rr8+7, cols cc..cc+3 ---
        {
            float aK[8][4], aV[8][4];
            #pragma unroll
            for (int a = 0; a < 8; ++a)
                #pragma unroll
                for (int b = 0; b < 4; ++b) { aK[a][b] = 0.f; aV[a][b] = 0.f; }
            for (int k = 0; k < DIM; ++k) {
                const float4 wK = *(const float4*)(Kw + (size_t)k*DIM + cc);
                const float4 wV = *(const float4*)(Vw + (size_t)k*DIM + cc);
                #pragma unroll
                for (int rq = 0; rq < 8; ++rq) {
                    const float h = hb[(rr8 + rq)*DIM + k];
                    aK[rq][0] += h*wK.x; aK[rq][1] += h*wK.y;
                    aK[rq][2] += h*wK.z; aK[rq][3] += h*wK.w;
                    aV[rq][0] += h*wV.x; aV[rq][1] += h*wV.y;
                    aV[rq][2] += h*wV.z; aV[rq][3] += h*wV.w;
                }
            }
            #pragma unroll
            for (int rq = 0; rq < 8; ++rq) {
                *(float4*)&Kt[(rr8 + rq)*DIM + cc] =
                    make_float4(aK[rq][0], aK[rq][1], aK[rq][2], aK[rq][3]);
                *(float4*)&Vt[(rr8 + rq)*DIM + cc] =
                    make_float4(aV[rq][0], aV[rq][1], aV[rq][2], aV[rq][3]);
            }
        }
        __syncthreads();
        // --- KtV partial: accP[j'] += sum_r Kt[r][i] * Vt[r][j0+j'] ---
        for (int r = 0; r < CHUNK; ++r) {
            const float kv = Kt[r*DIM + i];
            #pragma unroll
            for (int j4 = 0; j4 < 16; ++j4) {
                const float4 v = *(const float4*)&Vt[r*DIM + j0 + j4*4];
                accP[j4*4+0] += kv*v.x; accP[j4*4+1] += kv*v.y;
                accP[j4*4+2] += kv*v.z; accP[j4*4+3] += kv*v.w;
            }
        }
        __syncthreads();
    }
    float* S = slots + (size_t)(blockIdx.x & (NSLOT-1)) * 16384;
    for (int p = 0; p < 64; ++p) atomicAdd(&S[i*DIM + j0 + p], accP[p]);
}

// Reduce NSLOT partial KtV matrices -> ktv (fp32, 128x128)
__global__ void kReduce(const float* __restrict__ slots, float* __restrict__ ktv)
{
    const int e = blockIdx.x*256 + threadIdx.x;  // 16384 threads
    float s = 0.f;
    #pragma unroll
    for (int b = 0; b < NSLOT; ++b) s += slots[(size_t)b*16384 + e];
    ktv[e] = s;
}

// M = Qw @ KtV (fp32), stored row-major M[k][j]
__global__ void kBuildM(const float* __restrict__ Qw, const float* __restrict__ ktv,
                        float* __restrict__ M)
{
    const int idx = blockIdx.x*256 + threadIdx.x;  // 16384
    const int k = idx >> 7, j = idx & 127;
    float s = 0.f;
    for (int i = 0; i < 128; ++i) s += Qw[k*128 + i] * ktv[i*128 + j];
    M[idx] = s;
}

// ---------------------------------------------------------------------------
// Kernel B (fp32): x += h1 @ M ; LN2 ; x += relu(h2@w1+b1)@w2 + b2  (in-place safe)
// ---------------------------------------------------------------------------
__global__ __launch_bounds__(256, 1)
void kB32(const float* __restrict__ xin, float* __restrict__ xout,
          const float* __restrict__ M,
          const float* __restrict__ g1a, const float* __restrict__ b1a,
          const float* __restrict__ g2a, const float* __restrict__ b2a,
          const float* __restrict__ w1,  const float* __restrict__ fb1,
          const float* __restrict__ w2,  const float* __restrict__ fb2)
{
    __shared__ float xb[CHUNK*DIM];    // residual tile
    __shared__ float hb[CHUNK*DIM];    // LN output tile
    __shared__ float fh[CHUNK*256];    // relu(ff) half tile
    const int tid  = threadIdx.x;
    const int wv   = tid >> 6, lane = tid & 63;
    const int cc   = (tid & 31) * 4;   // dx/dx2: cols cc..cc+3
    const int rr8  = (tid >> 5) * 8;   // dx/dx2: rows rr8..rr8+7
    const int fc   = (tid & 63) * 4;   // f: local cols fc..fc+3 (<256)
    const int fr   = (tid >> 6) * 16;  // f: rows fr..fr+15

    const float g10 = g1a[2*lane], g11 = g1a[2*lane+1];
    const float b10 = b1a[2*lane], b11 = b1a[2*lane+1];
    const float g20 = g2a[2*lane], g21 = g2a[2*lane+1];
    const float b20 = b2a[2*lane], b21 = b2a[2*lane+1];

    for (int ch = 0; ch < NCHUNK; ++ch) {
        const size_t r0 = ((size_t)blockIdx.x * NCHUNK + ch) * CHUNK;
        // --- stage x chunk (coalesced float4) ---
        #pragma unroll
        for (int t = 0; t < 8; ++t) {
            const int idx = tid + t*256;
            const int r = idx >> 5, c = (idx & 31)*4;
            *(float4*)&xb[r*DIM + c] = *(const float4*)(xin + (r0 + r)*DIM + c);
        }
        __syncthreads();
        // --- LN1: xb -> hb ---
        for (int rr = 0; rr < 16; ++rr) {
            const int r = wv*16 + rr;
            const float2 xv = *(const float2*)(xb + r*DIM + 2*lane);
            float s = xv.x + xv.y, q = xv.x*xv.x + xv.y*xv.y;
            #pragma unroll
            for (int o = 1; o < 64; o <<= 1) { s += __shfl_xor(s, o); q += __shfl_xor(q, o); }
            const float m  = s * (1.0f/128.0f);
            const float rs = rsqrtf(q * (1.0f/128.0f) - m*m + 1e-5f);
            hb[r*DIM + 2*lane]     = (xv.x - m)*rs*g10 + b10;
            hb[r*DIM + 2*lane + 1] = (xv.y - m)*rs*g11 + b11;
        }
        __syncthreads();
        // --- dx = h1 @ M, accumulate into xb ---
        {
            float aD[8][4];
            #pragma unroll
            for (int a = 0; a < 8; ++a)
                #pragma unroll
                for (int b = 0; b < 4; ++b) aD[a][b] = 0.f;
            for (int k = 0; k < DIM; ++k) {
                const float4 m4 = *(const float4*)(M + (size_t)k*DIM + cc);
                #pragma unroll
                for (int rq = 0; rq < 8; ++rq) {
                    const float h = hb[(rr8 + rq)*DIM + k];
                    aD[rq][0] += h*m4.x; aD[rq][1] += h*m4.y;
                    aD[rq][2] += h*m4.z; aD[rq][3] += h*m4.w;
                }
            }
            #pragma unroll
            for (int rq = 0; rq < 8; ++rq)
                #pragma unroll
                for (int b = 0; b < 4; ++b)
                    xb[(rr8 + rq)*DIM + cc + b] += aD[rq][b];
        }
        __syncthreads();
        // --- LN2: xb -> hb ---
        for (int rr = 0; rr < 16; ++rr) {
            const int r = wv*16 + rr;
            const float2 xv = *(const float2*)(xb + r*DIM + 2*lane);
            float s = xv.x + xv.y, q = xv.x*xv.x + xv.y*xv.y;
            #pragma unroll
            for (int o = 1; o < 64; o <<= 1) { s += __shfl_xor(s, o); q += __shfl_xor(q, o); }
            const float m  = s * (1.0f/128.0f);
            const float rs = rsqrtf(q * (1.0f/128.0f) - m*m + 1e-5f);
            hb[r*DIM + 2*lane]     = (xv.x - m)*rs*g20 + b20;
            hb[r*DIM + 2*lane + 1] = (xv.y - m)*rs*g21 + b21;
        }
        __syncthreads();
        // --- FF in two 256-col halves; dx2 accumulated across halves ---
        float aX[8][4];
        #pragma unroll
        for (int a = 0; a < 8; ++a)
            #pragma unroll
            for (int b = 0; b < 4; ++b) aX[a][b] = 0.f;
        for (int hf = 0; hf < 2; ++hf) {
            // f = relu(h2 @ w1[:, hf-half] + b1): thread -> rows fr..fr+15, cols fc..fc+3
            {
                float aF[16][4];
                #pragma unroll
                for (int a = 0; a < 16; ++a)
                    #pragma unroll
                    for (int b = 0; b < 4; ++b) aF[a][b] = 0.f;
                for (int k = 0; k < DIM; ++k) {
                    const float4 w4 = *(const float4*)(w1 + (size_t)k*FFD + hf*256 + fc);
                    #pragma unroll
                    for (int rq = 0; rq < 16; ++rq) {
                        const float h = hb[(fr + rq)*DIM + k];
                        aF[rq][0] += h*w4.x; aF[rq][1] += h*w4.y;
                        aF[rq][2] += h*w4.z; aF[rq][3] += h*w4.w;
                    }
                }
                #pragma unroll
                for (int rq = 0; rq < 16; ++rq)
                    #pragma unroll
                    for (int b = 0; b < 4; ++b) {
                        const float v = aF[rq][b] + fb1[hf*256 + fc + b];
                        fh[(fr + rq)*256 + fc + b] = v > 0.f ? v : 0.f;
                    }
            }
            __syncthreads();
            // dx2 += f @ w2[hf-half, :]: thread -> rows rr8..rr8+7, cols cc..cc+3
            for (int k = 0; k < 256; ++k) {
                const float4 w4 = *(const float4*)(w2 + (size_t)(hf*256 + k)*DIM + cc);
                #pragma unroll
                for (int rq = 0; rq < 8; ++rq) {
                    const float f = fh[(rr8 + rq)*256 + k];
                    aX[rq][0] += f*w4.x; aX[rq][1] += f*w4.y;
                    aX[rq][2] += f*w4.z; aX[rq][3] += f*w4.w;
                }
            }
            __syncthreads();
        }
        // --- epilogue: xb += dx2 + b2 ---
        #pragma unroll
        for (int rq = 0; rq < 8; ++rq)
            #pragma unroll
            for (int b = 0; b < 4; ++b)
                xb[(rr8 + rq)*DIM + cc + b] += aX[rq][b] + fb2[cc + b];
        __syncthreads();
        // --- coalesced store (in-place safe: block owns its rows) ---
        #pragma unroll
        for (int t = 0; t < 8; ++t) {
            const int idx = tid + t*256;
            const int r = idx >> 5, c = (idx & 31)*4;
            *(float4*)(xout + (r0 + r)*DIM + c) = *(const float4*)&xb[r*DIM + c];
        }
        __syncthreads();
    }
}

// ---------------------------------------------------------------------------
// Final (fp32): out = x @ out_w + out_b   (in-place safe on d_out)
// ---------------------------------------------------------------------------
__global__ __launch_bounds__(256, 1)
void kF32(const float* __restrict__ x, const float* __restrict__ Ow,
          const float* __restrict__ ob, float* __restrict__ out)
{
    __shared__ float xb[CHUNK*DIM];
    const int tid = threadIdx.x;
    const int cc  = (tid & 31) * 4;
    const int rr8 = (tid >> 5) * 8;

    for (int ch = 0; ch < NCHUNK; ++ch) {
        const size_t r0 = ((size_t)blockIdx.x * NCHUNK + ch) * CHUNK;
        #pragma unroll
        for (int t = 0; t < 8; ++t) {
            const int idx = tid + t*256;
            const int r = idx >> 5, c = (idx & 31)*4;
            *(float4*)&xb[r*DIM + c] = *(const float4*)(x + (r0 + r)*DIM + c);
        }
        __syncthreads();
        float aD[8][4];
        #pragma unroll
        for (int a = 0; a < 8; ++a)
            #pragma unroll
            for (int b = 0; b < 4; ++b) aD[a][b] = 0.f;
        for (int k = 0; k < DIM; ++k) {
            const float4 w4 = *(const float4*)(Ow + (size_t)k*DIM + cc);
            #pragma unroll
            for (int rq = 0; rq < 8; ++rq) {
                const float h = xb[(rr8 + rq)*DIM + k];
                aD[rq][0] += h*w4.x; aD[rq][1] += h*w4.y;
                aD[rq][2] += h*w4.z; aD[rq][3] += h*w4.w;
            }
        }
        #pragma unroll
        for (int rq = 0; rq < 8; ++rq) {
            float4 o4 = make_float4(aD[rq][0] + ob[cc+0], aD[rq][1] + ob[cc+1],
                                    aD[rq][2] + ob[cc+2], aD[rq][3] + ob[cc+3]);
            *(float4*)(out + (r0 + rr8 + rq)*DIM + cc) = o4;
        }
        __syncthreads();
    }
}

extern "C" void kernel_launch(void* const* d_in, const int* in_sizes, int n_in,
                              void* d_out, int out_size, void* d_ws, size_t ws_size,
                              hipStream_t stream)
{
    (void)in_sizes; (void)n_in; (void)out_size; (void)ws_size;
    const float* x_in = (const float*)d_in[0];
    const float* Kw   = (const float*)d_in[1];
    const float* Qw   = (const float*)d_in[2];
    const float* Vw   = (const float*)d_in[3];
    const float* ln1g = (const float*)d_in[4];
    const float* ln1b = (const float*)d_in[5];
    const float* ln2g = (const float*)d_in[6];
    const float* ln2b = (const float*)d_in[7];
    const float* w1   = (const float*)d_in[8];
    const float* b1   = (const float*)d_in[9];
    const float* w2   = (const float*)d_in[10];
    const float* b2   = (const float*)d_in[11];
    const float* Ow   = (const float*)d_in[12];
    const float* ob   = (const float*)d_in[13];

    // Workspace (~1.13 MiB): KtV slots + ktv + M. x ping-pongs in d_out.
    char* p = (char*)d_ws;
    float* slots = (float*)p; p += (size_t)NSLOT*16384*4;
    float* ktv   = (float*)p; p += 16384*4;
    float* M     = (float*)p; p += 16384*4;

    float* X = (float*)d_out;   // 131072 x 128 fp32 working buffer == output buffer

    const float* src = x_in;
    for (int t = 0; t < TSTEPS; ++t) {
        hipMemsetAsync(slots, 0, (size_t)NSLOT*16384*4, stream);
        kA32<<<NBLK, 256, 0, stream>>>(src, Kw, Vw, ln1g, ln1b, slots);
        kReduce<<<64, 256, 0, stream>>>(slots, ktv);
        kBuildM<<<64, 256, 0, stream>>>(Qw, ktv, M);
        kB32<<<NBLK, 256, 0, stream>>>(src, X, M, ln1g, ln1b, ln2g, ln2b,
                                       w1, b1, w2, b2);
        src = X;
    }
    kF32<<<NBLK, 256, 0, stream>>>(X, Ow, ob, (float*)d_out);
}

// Round 4
// 1326.385 us; speedup vs baseline: 4.6638x; 4.6638x over previous
//
#include <hip/hip_runtime.h>

#define NROWS 131072
#define DIM   128
#define FFD   512
#define TSTEPS 4
#define NBLK  512
#define CHUNK 64
#define NCHUNK 4   // NROWS / (NBLK*CHUNK)
#define NSLOT 16
#define SH    136  // stride for 128-wide bf16 LDS tiles (16B-aligned rows)
#define SKV   72   // stride for 64-wide bf16 LDS tiles (KT/VT)

static_assert((long)NBLK * CHUNK * NCHUNK == NROWS, "grid/chunk mismatch");

typedef short          s8v   __attribute__((ext_vector_type(8)));
typedef float          f4v   __attribute__((ext_vector_type(4)));
typedef unsigned short u16x4 __attribute__((ext_vector_type(4)));

#define MFMA16(a,b,c) __builtin_amdgcn_mfma_f32_16x16x32_bf16((a),(b),(c),0,0,0)

__device__ __forceinline__ unsigned short f2bf(float f){
    unsigned u = __builtin_bit_cast(unsigned, f);
    u += 0x7FFFu + ((u >> 16) & 1u);   // round-to-nearest-even
    return (unsigned short)(u >> 16);
}
__device__ __forceinline__ float bf2f(unsigned short h){
    return __builtin_bit_cast(float, (unsigned)h << 16);
}

// LayerNorm of one 128-wide row held 2-elems/lane across a 64-lane wave.
__device__ __forceinline__ float2 ln_pair(float2 xv, float g0, float g1, float b0, float b1){
    float s = xv.x + xv.y;
    float q = xv.x*xv.x + xv.y*xv.y;
    #pragma unroll
    for (int o = 1; o < 64; o <<= 1) { s += __shfl_xor(s, o); q += __shfl_xor(q, o); }
    const float m  = s * (1.0f/128.0f);
    const float rs = rsqrtf(q * (1.0f/128.0f) - m*m + 1e-5f);
    return make_float2((xv.x - m)*rs*g0 + b0, (xv.y - m)*rs*g1 + b1);
}

template<bool SPLIT>
__device__ __forceinline__ void store_h(unsigned short* hi, unsigned short* lo,
                                        int off, float2 h){
    const unsigned short h0 = f2bf(h.x), h1 = f2bf(h.y);
    *(unsigned*)&hi[off] = (unsigned)h0 | ((unsigned)h1 << 16);
    if (SPLIT) {
        const unsigned short l0 = f2bf(h.x - bf2f(h0)), l1 = f2bf(h.y - bf2f(h1));
        *(unsigned*)&lo[off] = (unsigned)l0 | ((unsigned)l1 << 16);
    }
}

// ---------------------------------------------------------------------------
// Kernel A: LN1 (split bf16), K/V projections, per-block partial KtV -> atomic slots.
// ---------------------------------------------------------------------------
__global__ __launch_bounds__(256, 2)
void kA(const float* __restrict__ x, const unsigned short* __restrict__ Kwp,
        const unsigned short* __restrict__ Vwp,
        const float* __restrict__ ga, const float* __restrict__ be,
        float* __restrict__ slots)
{
    __shared__ unsigned short hh[64*SH];    // h1 bf16 hi  (64 rows x 128 cols, stride 136)
    __shared__ unsigned short hl[64*SH];    // h1 bf16 lo
    __shared__ unsigned short KT[128*SKV];  // K^T bf16: KT[c][r] (128 rows x 64 cols)
    __shared__ unsigned short VT[128*SKV];
    const int tid  = threadIdx.x;
    const int wv   = tid >> 6, lane = tid & 63;
    const int quad = lane >> 4, l15 = lane & 15;

    f4v acc[16];  // wave wv owns KtV rows [wv*32, wv*32+32): 2 x 8 tiles
    #pragma unroll
    for (int i = 0; i < 16; ++i) acc[i] = (f4v){0.f,0.f,0.f,0.f};

    const float g0 = ga[2*lane], g1 = ga[2*lane+1];
    const float b0 = be[2*lane], b1 = be[2*lane+1];

    for (int ch = 0; ch < NCHUNK; ++ch) {
        const size_t r0 = ((size_t)blockIdx.x*NCHUNK + ch)*CHUNK;
        // --- LN1 straight from global, split bf16 into LDS ---
        #pragma unroll
        for (int rr = 0; rr < 16; ++rr) {
            const int r = wv*16 + rr;
            const float2 xv = *(const float2*)(x + (r0 + r)*DIM + 2*lane);
            store_h<true>(hh, hl, r*SH + 2*lane, ln_pair(xv, g0, g1, b0, b1));
        }
        __syncthreads();
        // --- K and V projections: M=64, N=128, K=128; wave wv -> cols [wv*32,+32) ---
        #pragma unroll
        for (int p = 0; p < 2; ++p) {
            const unsigned short* Wp = p ? Vwp : Kwp;
            unsigned short* T = p ? VT : KT;
            s8v bf[2][4];
            #pragma unroll
            for (int nt = 0; nt < 2; ++nt)
                #pragma unroll
                for (int ks = 0; ks < 4; ++ks)
                    bf[nt][ks] = *(const s8v*)(Wp + (wv*32 + nt*16 + l15)*DIM + ks*32 + quad*8);
            #pragma unroll
            for (int mt = 0; mt < 4; ++mt) {
                s8v ah[4], al[4];
                #pragma unroll
                for (int ks = 0; ks < 4; ++ks) {
                    ah[ks] = *(const s8v*)(&hh[(mt*16 + l15)*SH + ks*32 + quad*8]);
                    al[ks] = *(const s8v*)(&hl[(mt*16 + l15)*SH + ks*32 + quad*8]);
                }
                #pragma unroll
                for (int nt = 0; nt < 2; ++nt) {
                    f4v c = {0.f,0.f,0.f,0.f};
                    #pragma unroll
                    for (int ks = 0; ks < 4; ++ks) c = MFMA16(ah[ks], bf[nt][ks], c);
                    #pragma unroll
                    for (int ks = 0; ks < 4; ++ks) c = MFMA16(al[ks], bf[nt][ks], c);
                    // C layout: row=quad*4+reg, col=l15 -> store transposed T[col][row]
                    u16x4 w4 = { f2bf(c[0]), f2bf(c[1]), f2bf(c[2]), f2bf(c[3]) };
                    *(u16x4*)&T[(wv*32 + nt*16 + l15)*SKV + mt*16 + quad*4] = w4;
                }
            }
        }
        __syncthreads();
        // --- KtV += K_chunk^T @ V_chunk: M=128(i), N=128(j), K=64(rows) ---
        #pragma unroll
        for (int ks = 0; ks < 2; ++ks) {
            s8v af[2];
            #pragma unroll
            for (int it = 0; it < 2; ++it)
                af[it] = *(const s8v*)(&KT[(wv*32 + it*16 + l15)*SKV + ks*32 + quad*8]);
            #pragma unroll
            for (int jt = 0; jt < 8; ++jt) {
                const s8v bfr = *(const s8v*)(&VT[(jt*16 + l15)*SKV + ks*32 + quad*8]);
                #pragma unroll
                for (int it = 0; it < 2; ++it)
                    acc[jt*2 + it] = MFMA16(af[it], bfr, acc[jt*2 + it]);
            }
        }
        __syncthreads();
    }
    // --- accumulate partial KtV into one of NSLOT slots (fp32 atomics) ---
    float* S = slots + (size_t)(blockIdx.x & (NSLOT-1)) * 16384;
    #pragma unroll
    for (int jt = 0; jt < 8; ++jt)
        #pragma unroll
        for (int it = 0; it < 2; ++it) {
            const int i0 = wv*32 + it*16 + quad*4;
            const int j  = jt*16 + l15;
            #pragma unroll
            for (int rg = 0; rg < 4; ++rg)
                atomicAdd(&S[(i0 + rg)*DIM + j], acc[jt*2 + it][rg]);
        }
}

// Reduce NSLOT partial KtV matrices -> ktv (fp32, 128x128)
__global__ void kReduce(const float* __restrict__ slots, float* __restrict__ ktv)
{
    const int e = blockIdx.x*256 + threadIdx.x;  // 16384 threads
    float s = 0.f;
    #pragma unroll
    for (int b = 0; b < NSLOT; ++b) s += slots[(size_t)b*16384 + e];
    ktv[e] = s;
}

// M = Qw @ KtV (fp32), packed split bf16 as Mp/Ml[j][k] (B-operand [n][k] layout)
__global__ void kBuildM(const float* __restrict__ Qw, const float* __restrict__ ktv,
                        unsigned short* __restrict__ Mp, unsigned short* __restrict__ Ml)
{
    const int idx = blockIdx.x*256 + threadIdx.x;  // 16384
    const int j = idx >> 7, k = idx & 127;
    float s = 0.f;
    for (int i = 0; i < 128; ++i) s += Qw[k*128 + i] * ktv[i*128 + j];
    const unsigned short hi = f2bf(s);
    Mp[idx] = hi;
    Ml[idx] = f2bf(s - bf2f(hi));
}

// ---------------------------------------------------------------------------
// Kernel B: x += h1 @ M ; LN2 ; x += relu(h2@w1+b1)@w2 + b2   (in-place safe)
// ---------------------------------------------------------------------------
__global__ __launch_bounds__(256, 2)
void kB(const float* __restrict__ xin, float* __restrict__ xout,
        const unsigned short* __restrict__ Mp, const unsigned short* __restrict__ Ml,
        const float* __restrict__ g1a, const float* __restrict__ b1a,
        const float* __restrict__ g2a, const float* __restrict__ b2a,
        const unsigned short* __restrict__ w1p, const float* __restrict__ fb1,
        const unsigned short* __restrict__ w2p, const float* __restrict__ fb2)
{
    __shared__ float          xb[64*132];  // fp32 residual tile, stride 132
    __shared__ unsigned short hs[64*SH];   // bf16 LN output (hi)
    __shared__ unsigned short fb[64*SH];   // bf16 relu(ff) quarter; reused as h1-lo in GEMM1
    unsigned short* const hl = fb;
    const int tid  = threadIdx.x;
    const int wv   = tid >> 6, lane = tid & 63;
    const int quad = lane >> 4, l15 = lane & 15;

    const float g10 = g1a[2*lane], g11 = g1a[2*lane+1];
    const float b10 = b1a[2*lane], b11 = b1a[2*lane+1];
    const float g20 = g2a[2*lane], g21 = g2a[2*lane+1];
    const float b20 = b2a[2*lane], b21 = b2a[2*lane+1];

    for (int ch = 0; ch < NCHUNK; ++ch) {
        const size_t r0 = ((size_t)blockIdx.x*NCHUNK + ch)*CHUNK;
        // --- stage x chunk into LDS (coalesced float4) ---
        #pragma unroll
        for (int i = 0; i < 8; ++i) {
            const int idx = tid + i*256;          // float4 index; 32 per row
            const int r = idx >> 5, c = (idx & 31)*4;
            *(float4*)&xb[r*132 + c] = *(const float4*)(xin + (r0 + r)*DIM + c);
        }
        __syncthreads();
        // --- LN1 (split) ---
        #pragma unroll
        for (int rr = 0; rr < 16; ++rr) {
            const int r = wv*16 + rr;
            const float2 xv = *(const float2*)(xb + r*132 + 2*lane);
            store_h<true>(hs, hl, r*SH + 2*lane, ln_pair(xv, g10, g11, b10, b11));
        }
        __syncthreads();
        // --- GEMM1: dx = h1 @ M (3-way split: Ah*Mh + Ah*Ml + Al*Mh) ---
        {
            s8v bh[2][4], bl[2][4];
            #pragma unroll
            for (int nt = 0; nt < 2; ++nt)
                #pragma unroll
                for (int ks = 0; ks < 4; ++ks) {
                    bh[nt][ks] = *(const s8v*)(Mp + (wv*32 + nt*16 + l15)*DIM + ks*32 + quad*8);
                    bl[nt][ks] = *(const s8v*)(Ml + (wv*32 + nt*16 + l15)*DIM + ks*32 + quad*8);
                }
            #pragma unroll
            for (int mt = 0; mt < 4; ++mt) {
                s8v ah[4], al[4];
                #pragma unroll
                for (int ks = 0; ks < 4; ++ks) {
                    ah[ks] = *(const s8v*)(&hs[(mt*16 + l15)*SH + ks*32 + quad*8]);
                    al[ks] = *(const s8v*)(&hl[(mt*16 + l15)*SH + ks*32 + quad*8]);
                }
                #pragma unroll
                for (int nt = 0; nt < 2; ++nt) {
                    f4v c = {0.f,0.f,0.f,0.f};
                    #pragma unroll
                    for (int ks = 0; ks < 4; ++ks) c = MFMA16(ah[ks], bh[nt][ks], c);
                    #pragma unroll
                    for (int ks = 0; ks < 4; ++ks) c = MFMA16(ah[ks], bl[nt][ks], c);
                    #pragma unroll
                    for (int ks = 0; ks < 4; ++ks) c = MFMA16(al[ks], bh[nt][ks], c);
                    const int cg = wv*32 + nt*16 + l15;
                    #pragma unroll
                    for (int rg = 0; rg < 4; ++rg)
                        xb[(mt*16 + quad*4 + rg)*132 + cg] += c[rg];
                }
            }
        }
        __syncthreads();
        // --- LN2 (hi only) ---
        #pragma unroll
        for (int rr = 0; rr < 16; ++rr) {
            const int r = wv*16 + rr;
            const float2 xv = *(const float2*)(xb + r*132 + 2*lane);
            store_h<false>(hs, nullptr, r*SH + 2*lane, ln_pair(xv, g20, g21, b20, b21));
        }
        __syncthreads();
        // --- FF: four quarters of 128 ff-cols; dx2 accumulated across quarters ---
        f4v dx2[8];
        #pragma unroll
        for (int i = 0; i < 8; ++i) dx2[i] = (f4v){0.f,0.f,0.f,0.f};
        #pragma unroll
        for (int qf = 0; qf < 4; ++qf) {
            // GEMM2a: f = relu(h2 @ w1[:, quarter] + b1); wave wv -> local cols [wv*32,+32)
            #pragma unroll
            for (int mt = 0; mt < 4; ++mt) {
                s8v af[4];
                #pragma unroll
                for (int ks = 0; ks < 4; ++ks)
                    af[ks] = *(const s8v*)(&hs[(mt*16 + l15)*SH + ks*32 + quad*8]);
                #pragma unroll
                for (int nt = 0; nt < 2; ++nt) {
                    const int fl  = wv*32 + nt*16 + l15;      // local ff col < 128
                    const int ffc = qf*128 + fl;              // global ff col
                    s8v bfr[4];
                    #pragma unroll
                    for (int ks = 0; ks < 4; ++ks)
                        bfr[ks] = *(const s8v*)(w1p + ffc*DIM + ks*32 + quad*8);
                    const float bias = fb1[ffc];
                    f4v c = {0.f,0.f,0.f,0.f};
                    #pragma unroll
                    for (int ks = 0; ks < 4; ++ks) c = MFMA16(af[ks], bfr[ks], c);
                    #pragma unroll
                    for (int rg = 0; rg < 4; ++rg) {
                        float v = c[rg] + bias;
                        v = v > 0.f ? v : 0.f;
                        fb[(mt*16 + quad*4 + rg)*SH + fl] = f2bf(v);
                    }
                }
            }
            __syncthreads();
            // GEMM2b: dx2 += f @ w2[quarter, :]; wave wv -> cols [wv*32,+32)
            #pragma unroll
            for (int mt = 0; mt < 4; ++mt) {
                s8v af[4];
                #pragma unroll
                for (int ks = 0; ks < 4; ++ks)
                    af[ks] = *(const s8v*)(&fb[(mt*16 + l15)*SH + ks*32 + quad*8]);
                #pragma unroll
                for (int nt = 0; nt < 2; ++nt) {
                    f4v c = dx2[mt*2 + nt];
                    #pragma unroll
                    for (int ks = 0; ks < 4; ++ks) {
                        const s8v bfr = *(const s8v*)(w2p + (wv*32 + nt*16 + l15)*FFD
                                                      + qf*128 + ks*32 + quad*8);
                        c = MFMA16(af[ks], bfr, c);
                    }
                    dx2[mt*2 + nt] = c;
                }
            }
            __syncthreads();
        }
        // --- epilogue: xb += dx2 + b2 ---
        #pragma unroll
        for (int nt = 0; nt < 2; ++nt) {
            const int cg = wv*32 + nt*16 + l15;
            const float bias = fb2[cg];
            #pragma unroll
            for (int mt = 0; mt < 4; ++mt)
                #pragma unroll
                for (int rg = 0; rg < 4; ++rg)
                    xb[(mt*16 + quad*4 + rg)*132 + cg] += dx2[mt*2 + nt][rg] + bias;
        }
        __syncthreads();
        // --- coalesced store (in-place safe: block wrote only its own rows) ---
        #pragma unroll
        for (int i = 0; i < 8; ++i) {
            const int idx = tid + i*256;
            const int r = idx >> 5, c = (idx & 31)*4;
            *(float4*)(xout + (r0 + r)*DIM + c) = *(const float4*)&xb[r*132 + c];
        }
        __syncthreads();
    }
}

// ---------------------------------------------------------------------------
// Final: out = x @ out_w + out_b  (split-x, in-place safe on d_out)
// ---------------------------------------------------------------------------
__global__ __launch_bounds__(256, 2)
void kF(const float* __restrict__ x, const unsigned short* __restrict__ Owp,
        const float* __restrict__ ob, float* __restrict__ out)
{
    __shared__ unsigned short hh[64*SH];
    __shared__ unsigned short hl[64*SH];
    __shared__ float          xb[64*132];
    const int tid  = threadIdx.x;
    const int wv   = tid >> 6, lane = tid & 63;
    const int quad = lane >> 4, l15 = lane & 15;
    (void)wv; (void)lane;

    for (int ch = 0; ch < NCHUNK; ++ch) {
        const size_t r0 = ((size_t)blockIdx.x*NCHUNK + ch)*CHUNK;
        #pragma unroll
        for (int i = 0; i < 8; ++i) {
            const int idx = tid + i*256;
            const int r = idx >> 5, c = (idx & 31)*4;
            const float4 v = *(const float4*)(x + (r0 + r)*DIM + c);
            const unsigned short h0 = f2bf(v.x), h1 = f2bf(v.y),
                                 h2 = f2bf(v.z), h3 = f2bf(v.w);
            u16x4 w4 = { h0, h1, h2, h3 };
            u16x4 l4 = { f2bf(v.x - bf2f(h0)), f2bf(v.y - bf2f(h1)),
                         f2bf(v.z - bf2f(h2)), f2bf(v.w - bf2f(h3)) };
            *(u16x4*)&hh[r*SH + c] = w4;
            *(u16x4*)&hl[r*SH + c] = l4;
        }
        __syncthreads();
        {
            const int wv_ = tid >> 6;
            s8v bf[2][4];
            #pragma unroll
            for (int nt = 0; nt < 2; ++nt)
                #pragma unroll
                for (int ks = 0; ks < 4; ++ks)
                    bf[nt][ks] = *(const s8v*)(Owp + (wv_*32 + nt*16 + l15)*DIM + ks*32 + quad*8);
            #pragma unroll
            for (int mt = 0; mt < 4; ++mt) {
                s8v ah[4], al[4];
                #pragma unroll
                for (int ks = 0; ks < 4; ++ks) {
                    ah[ks] = *(const s8v*)(&hh[(mt*16 + l15)*SH + ks*32 + quad*8]);
                    al[ks] = *(const s8v*)(&hl[(mt*16 + l15)*SH + ks*32 + quad*8]);
                }
                #pragma unroll
                for (int nt = 0; nt < 2; ++nt) {
                    f4v c = {0.f,0.f,0.f,0.f};
                    #pragma unroll
                    for (int ks = 0; ks < 4; ++ks) c = MFMA16(ah[ks], bf[nt][ks], c);
                    #pragma unroll
                    for (int ks = 0; ks < 4; ++ks) c = MFMA16(al[ks], bf[nt][ks], c);
                    const int cg = wv_*32 + nt*16 + l15;
                    const float bias = ob[cg];
                    #pragma unroll
                    for (int rg = 0; rg < 4; ++rg)
                        xb[(mt*16 + quad*4 + rg)*132 + cg] = c[rg] + bias;
                }
            }
        }
        __syncthreads();
        #pragma unroll
        for (int i = 0; i < 8; ++i) {
            const int idx = tid + i*256;
            const int r = idx >> 5, c = (idx & 31)*4;
            *(float4*)(out + (r0 + r)*DIM + c) = *(const float4*)&xb[r*132 + c];
        }
        __syncthreads();
    }
}

// Pack weights to bf16, transposed to B-operand-friendly [n][k] layout.
__global__ void kPack(const float* __restrict__ Kw, const float* __restrict__ Vw,
                      const float* __restrict__ Ow, const float* __restrict__ w1,
                      const float* __restrict__ w2,
                      unsigned short* __restrict__ Kwp, unsigned short* __restrict__ Vwp,
                      unsigned short* __restrict__ Owp, unsigned short* __restrict__ w1p,
                      unsigned short* __restrict__ w2p)
{
    const int t = blockIdx.x*256 + threadIdx.x;  // 147456 total
    if (t < 16384) {
        const int n = t >> 7, k = t & 127;
        Kwp[t] = f2bf(Kw[k*128 + n]);
        Vwp[t] = f2bf(Vw[k*128 + n]);
        Owp[t] = f2bf(Ow[k*128 + n]);
    } else if (t < 16384 + 65536) {
        const int u = t - 16384;
        const int n = u >> 7, k = u & 127;      // w1: [128][512] -> w1p[n<512][k<128]
        w1p[u] = f2bf(w1[k*FFD + n]);
    } else {
        const int u = t - 16384 - 65536;
        const int n = u >> 9, k = u & 511;      // w2: [512][128] -> w2p[n<128][k<512]
        w2p[u] = f2bf(w2[k*DIM + n]);
    }
}

extern "C" void kernel_launch(void* const* d_in, const int* in_sizes, int n_in,
                              void* d_out, int out_size, void* d_ws, size_t ws_size,
                              hipStream_t stream)
{
    (void)in_sizes; (void)n_in; (void)out_size; (void)ws_size;
    const float* x_in = (const float*)d_in[0];
    const float* Kw   = (const float*)d_in[1];
    const float* Qw   = (const float*)d_in[2];
    const float* Vw   = (const float*)d_in[3];
    const float* ln1g = (const float*)d_in[4];
    const float* ln1b = (const float*)d_in[5];
    const float* ln2g = (const float*)d_in[6];
    const float* ln2b = (const float*)d_in[7];
    const float* w1   = (const float*)d_in[8];
    const float* b1   = (const float*)d_in[9];
    const float* w2   = (const float*)d_in[10];
    const float* b2   = (const float*)d_in[11];
    const float* Ow   = (const float*)d_in[12];
    const float* ob   = (const float*)d_in[13];

    // Workspace (~1.5 MiB): x ping-pongs in d_out (in-place kernels).
    char* p = (char*)d_ws;
    float* slots        = (float*)p;          p += (size_t)NSLOT*16384*4;
    float* ktv          = (float*)p;          p += 16384*4;
    unsigned short* Kwp = (unsigned short*)p; p += 16384*2;
    unsigned short* Vwp = (unsigned short*)p; p += 16384*2;
    unsigned short* Owp = (unsigned short*)p; p += 16384*2;
    unsigned short* w1p = (unsigned short*)p; p += 65536*2;
    unsigned short* w2p = (unsigned short*)p; p += 65536*2;
    unsigned short* Mp  = (unsigned short*)p; p += 16384*2;
    unsigned short* Ml  = (unsigned short*)p; p += 16384*2;

    float* X = (float*)d_out;   // 131072 x 128 fp32 working buffer == output buffer

    kPack<<<576, 256, 0, stream>>>(Kw, Vw, Ow, w1, w2, Kwp, Vwp, Owp, w1p, w2p);

    const float* src = x_in;
    for (int t = 0; t < TSTEPS; ++t) {
        hipMemsetAsync(slots, 0, (size_t)NSLOT*16384*4, stream);
        kA<<<NBLK, 256, 0, stream>>>(src, Kwp, Vwp, ln1g, ln1b, slots);
        kReduce<<<64, 256, 0, stream>>>(slots, ktv);
        kBuildM<<<64, 256, 0, stream>>>(Qw, ktv, Mp, Ml);
        kB<<<NBLK, 256, 0, stream>>>(src, X, Mp, Ml, ln1g, ln1b, ln2g, ln2b,
                                     w1p, b1, w2p, b2);
        src = X;
    }
    kF<<<NBLK, 256, 0, stream>>>(X, Owp, ob, (float*)d_out);
}